// Round 2
// baseline (674.022 us; speedup 1.0000x reference)
//
#include <hip/hip_runtime.h>
#include <hip/hip_bf16.h>

#define RFn 500000
#define F1n 256
#define NFn 128
#define RAn 50000
#define LN_EPSn 1e-5f
#define SPB 25                          // segments per main-kernel block
#define NBLK ((RAn + SPB - 1) / SPB)    // 2000
#define FS 132                          // featw LDS row stride (floats): 4*FS%32==16 -> conflict-free

typedef float f32x4 __attribute__((ext_vector_type(4)));
typedef short short8 __attribute__((ext_vector_type(8)));

__device__ __forceinline__ short f2bf(float f) {
  __hip_bfloat16 h = __float2bfloat16(f);  // RNE
  return __builtin_bit_cast(short, h);
}

// ---------------------------------------------------------------------------
// Pack W_feat (256x128 f32) into MFMA B-frag image: frag (s,c), lane l:
// col = c*16+(l&15), k = s*32+(l>>4)*8+i  (8 bf16 per lane).
// ---------------------------------------------------------------------------
__global__ void prep_kernel(const float* __restrict__ Wf, short* __restrict__ frag) {
  int p = blockIdx.x * blockDim.x + threadIdx.x;  // 0..4095
  if (p >= 4096) return;
  int f = p >> 6, l = p & 63;
  int s = f >> 3, c = f & 7;
  int col = c * 16 + (l & 15);
  int k0 = s * 32 + ((l >> 4) << 3);
  short8 v;
#pragma unroll
  for (int i = 0; i < 8; ++i) v[i] = f2bf(Wf[(k0 + i) * NFn + col]);
  *(short8*)(frag + (size_t)p * 8) = v;
}

__global__ void hist_kernel(const int* __restrict__ ri, int* __restrict__ hist) {
  int i = blockIdx.x * 256 + threadIdx.x;
  if (i < RFn) atomicAdd(&hist[ri[i]], 1);
}

__global__ __launch_bounds__(1024) void scan_kernel(const int* __restrict__ hist,
                                                    int* __restrict__ rowstart,
                                                    int* __restrict__ cursor) {
  __shared__ int ls[1024];
  const int t = threadIdx.x;
  const int C = (RAn + 1023) / 1024;  // 49
  const int base = t * C;
  int sum = 0;
  for (int i = 0; i < C; ++i) {
    int idx = base + i;
    if (idx < RAn) sum += hist[idx];
  }
  ls[t] = sum;
  __syncthreads();
  for (int off = 1; off < 1024; off <<= 1) {
    int v = (t >= off) ? ls[t - off] : 0;
    __syncthreads();
    ls[t] += v;
    __syncthreads();
  }
  int run = (t == 0) ? 0 : ls[t - 1];
  for (int i = 0; i < C; ++i) {
    int idx = base + i;
    if (idx < RAn) {
      rowstart[idx] = run;
      cursor[idx] = run;
      run += hist[idx];
    }
  }
  if (t == 1023) rowstart[RAn] = ls[1023];
}

__global__ void scatter_kernel(const int* __restrict__ ri, int* __restrict__ cursor,
                               int* __restrict__ perm, int* __restrict__ sseg) {
  int i = blockIdx.x * 256 + threadIdx.x;
  if (i < RFn) {
    int s = ri[i];
    int pos = atomicAdd(&cursor[s], 1);
    perm[pos] = i;
    sseg[pos] = s;
  }
}

// ---------------------------------------------------------------------------
// Main: block owns segments [s0,s1) = sorted rows [rbeg,rend). 128-row tiles,
// 4 waves x 32 rows. MFMA as round 1 (B-frags from global, L2-hot). Epilogue
// writes feat*w into padded LDS tile; serial per-column sweep accumulates
// per-segment sums in registers, one coalesced store per segment (num/den).
// ---------------------------------------------------------------------------
__global__ __launch_bounds__(256) void main_kernel(
    const float* __restrict__ X, const short* __restrict__ fragWS,
    const float* __restrict__ Wa, const float* __restrict__ ba,
    const float* __restrict__ bfeat, const float* __restrict__ gamma,
    const float* __restrict__ beta, const int* __restrict__ rowstart,
    const int* __restrict__ perm, const int* __restrict__ sseg,
    float* __restrict__ out) {
  __shared__ float featw[128 * FS];
  __shared__ float wlds[128];
  __shared__ int segrow[128];

  const int tid = threadIdx.x;
  const int lane = tid & 63;
  const int wv = tid >> 6;
  const int colb = lane & 15;
  const int kg = lane >> 4;

  const int s0 = blockIdx.x * SPB;
  const int s1 = min(s0 + SPB, RAn);
  const int rbeg = rowstart[s0];
  const int rend = rowstart[s1];
  const int nrows = rend - rbeg;
  if (nrows <= 0) return;  // empty range: out stays memset-0

  float g_r[8], be_r[8], bi_r[8];
#pragma unroll
  for (int c = 0; c < 8; ++c) {
    int col = c * 16 + colb;
    g_r[c] = gamma[col];
    be_r[c] = beta[col];
    bi_r[c] = bfeat[col];
  }
  const float batn = ba[0];

  float accrun = 0.f, wrun = 0.f;
  int curseg = -1;

  const int ntile = (nrows + 127) >> 7;
  for (int t = 0; t < ntile; ++t) {
    const int tb = t << 7;
    const int pos0 = rbeg + tb + wv * 32 + colb;
    const int pos1 = pos0 + 16;
    const int row0 = (pos0 < rend) ? perm[pos0] : 0;
    const int row1 = (pos1 < rend) ? perm[pos1] : 0;
    const int sg0 = (pos0 < rend) ? sseg[pos0] : 0;
    const int sg1 = (pos1 < rend) ? sseg[pos1] : 0;
    const float* xp0 = X + (size_t)row0 * F1n + kg * 8;
    const float* xp1 = X + (size_t)row1 * F1n + kg * 8;

    f32x4 acc[2][8];
#pragma unroll
    for (int rt = 0; rt < 2; ++rt)
#pragma unroll
      for (int c = 0; c < 8; ++c) acc[rt][c] = (f32x4)(0.0f);
    float logit[2] = {0.f, 0.f};

#pragma unroll
    for (int s = 0; s < 8; ++s) {
      short8 bfr[8];
#pragma unroll
      for (int c = 0; c < 8; ++c)
        bfr[c] = *(const short8*)(fragWS + (((s * 8 + c) * 64 + lane) * 8));
      const float4 wa0 = *(const float4*)(Wa + s * 32 + kg * 8);
      const float4 wa1 = *(const float4*)(Wa + s * 32 + kg * 8 + 4);
#pragma unroll
      for (int rt = 0; rt < 2; ++rt) {
        const float* xp = rt ? xp1 : xp0;
        const float4 x0 = *(const float4*)(xp + s * 32);
        const float4 x1 = *(const float4*)(xp + s * 32 + 4);
        float a0 = fmaxf(x0.x, 0.01f * x0.x);
        float a1 = fmaxf(x0.y, 0.01f * x0.y);
        float a2 = fmaxf(x0.z, 0.01f * x0.z);
        float a3 = fmaxf(x0.w, 0.01f * x0.w);
        float a4 = fmaxf(x1.x, 0.01f * x1.x);
        float a5 = fmaxf(x1.y, 0.01f * x1.y);
        float a6 = fmaxf(x1.z, 0.01f * x1.z);
        float a7 = fmaxf(x1.w, 0.01f * x1.w);
        logit[rt] += a0 * wa0.x + a1 * wa0.y + a2 * wa0.z + a3 * wa0.w +
                     a4 * wa1.x + a5 * wa1.y + a6 * wa1.z + a7 * wa1.w;
        short8 af;
        af[0] = f2bf(a0); af[1] = f2bf(a1); af[2] = f2bf(a2); af[3] = f2bf(a3);
        af[4] = f2bf(a4); af[5] = f2bf(a5); af[6] = f2bf(a6); af[7] = f2bf(a7);
#pragma unroll
        for (int c = 0; c < 8; ++c)
          acc[rt][c] = __builtin_amdgcn_mfma_f32_16x16x32_bf16(af, bfr[c],
                                                               acc[rt][c], 0, 0, 0);
      }
    }

    // -------- epilogue: w, LN, stage feat*w into LDS --------
#pragma unroll
    for (int rt = 0; rt < 2; ++rt) {
      float lg = logit[rt];
      lg += __shfl_xor(lg, 16);
      lg += __shfl_xor(lg, 32);
      const float wexp = __expf(lg + batn);
      const int rloc = wv * 32 + rt * 16 + colb;
      if (lane < 16) {
        segrow[rloc] = rt ? sg1 : sg0;
        wlds[rloc] = wexp;
      }

      float w4[4];
#pragma unroll
      for (int reg = 0; reg < 4; ++reg) w4[reg] = __shfl(wexp, kg * 4 + reg);

      float s1v[4] = {0.f, 0.f, 0.f, 0.f}, s2v[4] = {0.f, 0.f, 0.f, 0.f};
#pragma unroll
      for (int c = 0; c < 8; ++c)
#pragma unroll
        for (int reg = 0; reg < 4; ++reg) {
          float v = acc[rt][c][reg] + bi_r[c];
          acc[rt][c][reg] = v;
          s1v[reg] += v;
          s2v[reg] += v * v;
        }
#pragma unroll
      for (int off = 1; off <= 8; off <<= 1)
#pragma unroll
        for (int reg = 0; reg < 4; ++reg) {
          s1v[reg] += __shfl_xor(s1v[reg], off);
          s2v[reg] += __shfl_xor(s2v[reg], off);
        }
      float mu[4], rs[4];
#pragma unroll
      for (int reg = 0; reg < 4; ++reg) {
        mu[reg] = s1v[reg] * (1.0f / NFn);
        float var = s2v[reg] * (1.0f / NFn) - mu[reg] * mu[reg];
        rs[reg] = rsqrtf(var + LN_EPSn);
      }
#pragma unroll
      for (int c = 0; c < 8; ++c)
#pragma unroll
        for (int reg = 0; reg < 4; ++reg) {
          float feat = (acc[rt][c][reg] - mu[reg]) * rs[reg] * g_r[c] + be_r[c];
          featw[(wv * 32 + rt * 16 + kg * 4 + reg) * FS + c * 16 + colb] =
              feat * w4[reg];
        }
    }
    __syncthreads();

    // -------- serial per-column segment accumulation --------
    if (tid < 128) {
      const int col = tid;
      const int nval = min(128, nrows - tb);
      for (int r = 0; r < nval; ++r) {
        const int s = segrow[r];
        const float w_ = wlds[r];
        const float v = featw[r * FS + col];
        if (s != curseg) {
          if (curseg >= 0) out[(size_t)curseg * NFn + col] = accrun / wrun;
          curseg = s;
          accrun = 0.f;
          wrun = 0.f;
        }
        accrun += v;
        wrun += w_;
      }
    }
    __syncthreads();
  }
  if (tid < 128 && curseg >= 0) out[(size_t)curseg * NFn + tid] = accrun / wrun;
}

extern "C" void kernel_launch(void* const* d_in, const int* in_sizes, int n_in,
                              void* d_out, int out_size, void* d_ws, size_t ws_size,
                              hipStream_t stream) {
  const float* X = (const float*)d_in[0];
  const float* Wf = (const float*)d_in[1];
  const float* bfeat = (const float*)d_in[2];
  const float* gamma = (const float*)d_in[3];
  const float* beta = (const float*)d_in[4];
  const float* Wa = (const float*)d_in[5];
  const float* ba = (const float*)d_in[6];
  const int* ri = (const int*)d_in[7];
  float* out = (float*)d_out;

  char* ws = (char*)d_ws;
  short* frag    = (short*)(ws);                 // 65,536 B
  int*   hist    = (int*)(ws + 65536);           // 200,704 B
  int*   rowstart= (int*)(ws + 266240);          // 200,704 B (RAn+1 ints)
  int*   cursor  = (int*)(ws + 466944);          // 200,704 B
  int*   perm    = (int*)(ws + 667648);          // 2,000,000 B
  int*   sseg    = (int*)(ws + 2667648);         // 2,000,000 B  (end ~4.67 MB)

  hipMemsetAsync(out, 0, (size_t)RAn * NFn * sizeof(float), stream);
  hipMemsetAsync(hist, 0, (size_t)RAn * sizeof(int), stream);

  prep_kernel<<<16, 256, 0, stream>>>(Wf, frag);
  hist_kernel<<<(RFn + 255) / 256, 256, 0, stream>>>(ri, hist);
  scan_kernel<<<1, 1024, 0, stream>>>(hist, rowstart, cursor);
  scatter_kernel<<<(RFn + 255) / 256, 256, 0, stream>>>(ri, cursor, perm, sseg);
  main_kernel<<<NBLK, 256, 0, stream>>>(X, frag, Wa, ba, bfeat, gamma, beta,
                                        rowstart, perm, sseg, out);
}

// Round 3
// 512.234 us; speedup vs baseline: 1.3158x; 1.3158x over previous
//
#include <hip/hip_runtime.h>
#include <hip/hip_bf16.h>

#define RFn 500000
#define F1n 256
#define NFn 128
#define RAn 50000
#define LN_EPSn 1e-5f
#define RECB 272   // record bytes: 128 bf16 feat*w + f32 w + 12B pad
#define RECS 136   // record shorts

typedef float f32x4 __attribute__((ext_vector_type(4)));
typedef short short8 __attribute__((ext_vector_type(8)));

__device__ __forceinline__ short f2bf(float f) {
  __hip_bfloat16 h = __float2bfloat16(f);  // RNE
  return __builtin_bit_cast(short, h);
}

// ---------------------------------------------------------------------------
// Pack W_feat (256x128 f32) into MFMA B-frag image: frag (s,c), lane l:
// col = c*16+(l&15), k = s*32+(l>>4)*8+i  (8 bf16 per lane).
// ---------------------------------------------------------------------------
__global__ void prep_kernel(const float* __restrict__ Wf, short* __restrict__ frag) {
  int p = blockIdx.x * blockDim.x + threadIdx.x;  // 0..4095
  if (p >= 4096) return;
  int f = p >> 6, l = p & 63;
  int s = f >> 3, c = f & 7;
  int col = c * 16 + (l & 15);
  int k0 = s * 32 + ((l >> 4) << 3);
  short8 v;
#pragma unroll
  for (int i = 0; i < 8; ++i) v[i] = f2bf(Wf[(k0 + i) * NFn + col]);
  *(short8*)(frag + (size_t)p * 8) = v;
}

__global__ void hist_kernel(const int* __restrict__ ri, int* __restrict__ hist) {
  int i = blockIdx.x * 256 + threadIdx.x;
  if (i < RFn) atomicAdd(&hist[ri[i]], 1);
}

__global__ __launch_bounds__(1024) void scan_kernel(const int* __restrict__ hist,
                                                    int* __restrict__ rowstart,
                                                    int* __restrict__ cursor) {
  __shared__ int ls[1024];
  const int t = threadIdx.x;
  const int C = (RAn + 1023) / 1024;  // 49
  const int base = t * C;
  int sum = 0;
  for (int i = 0; i < C; ++i) {
    int idx = base + i;
    if (idx < RAn) sum += hist[idx];
  }
  ls[t] = sum;
  __syncthreads();
  for (int off = 1; off < 1024; off <<= 1) {
    int v = (t >= off) ? ls[t - off] : 0;
    __syncthreads();
    ls[t] += v;
    __syncthreads();
  }
  int run = (t == 0) ? 0 : ls[t - 1];
  for (int i = 0; i < C; ++i) {
    int idx = base + i;
    if (idx < RAn) {
      rowstart[idx] = run;
      cursor[idx] = run;
      run += hist[idx];
    }
  }
  if (t == 1023) rowstart[RAn] = ls[1023];
}

// inv[i] = sorted position of original row i (segment-major order)
__global__ void scatter_kernel(const int* __restrict__ ri, int* __restrict__ cursor,
                               int* __restrict__ inv) {
  int i = blockIdx.x * 256 + threadIdx.x;
  if (i < RFn) inv[i] = atomicAdd(&cursor[ri[i]], 1);
}

// ---------------------------------------------------------------------------
// Phase A: streaming (rows in natural order). 4 waves x 32 rows = 128 rows
// per block. MFMA bf16 GEMM + in-register LN + logit/exp. Stage feat*w (bf16)
// and w (f32) into an LDS tile laid out exactly as the 272B output record,
// then write each row's record to buf at sorted position inv[row].
// ---------------------------------------------------------------------------
__global__ __launch_bounds__(256) void featw_kernel(
    const float* __restrict__ X, const short* __restrict__ fragWS,
    const float* __restrict__ Wa, const float* __restrict__ ba,
    const float* __restrict__ bfeat, const float* __restrict__ gamma,
    const float* __restrict__ beta, const int* __restrict__ inv,
    char* __restrict__ buf) {
  __shared__ __attribute__((aligned(16))) short lt[128 * RECS];  // 34816 B

  const int tid = threadIdx.x;
  const int lane = tid & 63;
  const int wv = tid >> 6;
  const int colb = lane & 15;
  const int kg = lane >> 4;
  const int rowbase = blockIdx.x * 128 + wv * 32;

  if (tid < 128) {  // zero record pad (slots 130..135)
    *(int*)&lt[tid * RECS + 130] = 0;
    *(int*)&lt[tid * RECS + 132] = 0;
    *(int*)&lt[tid * RECS + 134] = 0;
  }

  float g_r[8], be_r[8], bi_r[8];
#pragma unroll
  for (int c = 0; c < 8; ++c) {
    int col = c * 16 + colb;
    g_r[c] = gamma[col];
    be_r[c] = beta[col];
    bi_r[c] = bfeat[col];
  }
  const float batn = ba[0];

  f32x4 acc[2][8];
#pragma unroll
  for (int rt = 0; rt < 2; ++rt)
#pragma unroll
    for (int c = 0; c < 8; ++c) acc[rt][c] = (f32x4)(0.0f);
  float logit[2] = {0.f, 0.f};

  int gr0 = rowbase + colb;
  int gr1 = gr0 + 16;
  long r0 = (gr0 < RFn) ? gr0 : (RFn - 1);
  long r1 = (gr1 < RFn) ? gr1 : (RFn - 1);
  const float* xp0 = X + r0 * F1n + kg * 8;
  const float* xp1 = X + r1 * F1n + kg * 8;

#pragma unroll
  for (int s = 0; s < 8; ++s) {
    short8 bfr[8];
#pragma unroll
    for (int c = 0; c < 8; ++c)
      bfr[c] = *(const short8*)(fragWS + (((s * 8 + c) * 64 + lane) * 8));
    const float4 wa0 = *(const float4*)(Wa + s * 32 + kg * 8);
    const float4 wa1 = *(const float4*)(Wa + s * 32 + kg * 8 + 4);
#pragma unroll
    for (int rt = 0; rt < 2; ++rt) {
      const float* xp = rt ? xp1 : xp0;
      const float4 x0 = *(const float4*)(xp + s * 32);
      const float4 x1 = *(const float4*)(xp + s * 32 + 4);
      float a0 = fmaxf(x0.x, 0.01f * x0.x);
      float a1 = fmaxf(x0.y, 0.01f * x0.y);
      float a2 = fmaxf(x0.z, 0.01f * x0.z);
      float a3 = fmaxf(x0.w, 0.01f * x0.w);
      float a4 = fmaxf(x1.x, 0.01f * x1.x);
      float a5 = fmaxf(x1.y, 0.01f * x1.y);
      float a6 = fmaxf(x1.z, 0.01f * x1.z);
      float a7 = fmaxf(x1.w, 0.01f * x1.w);
      logit[rt] += a0 * wa0.x + a1 * wa0.y + a2 * wa0.z + a3 * wa0.w +
                   a4 * wa1.x + a5 * wa1.y + a6 * wa1.z + a7 * wa1.w;
      short8 af;
      af[0] = f2bf(a0); af[1] = f2bf(a1); af[2] = f2bf(a2); af[3] = f2bf(a3);
      af[4] = f2bf(a4); af[5] = f2bf(a5); af[6] = f2bf(a6); af[7] = f2bf(a7);
#pragma unroll
      for (int c = 0; c < 8; ++c)
        acc[rt][c] = __builtin_amdgcn_mfma_f32_16x16x32_bf16(af, bfr[c],
                                                             acc[rt][c], 0, 0, 0);
    }
  }

  // -------- epilogue: w, LN, stage record into LDS --------
#pragma unroll
  for (int rt = 0; rt < 2; ++rt) {
    float lg = logit[rt];
    lg += __shfl_xor(lg, 16);
    lg += __shfl_xor(lg, 32);
    const float wexp = __expf(lg + batn);
    const int rloc = wv * 32 + rt * 16 + colb;
    if (lane < 16) *(float*)&lt[rloc * RECS + 128] = wexp;

    float w4[4];
#pragma unroll
    for (int reg = 0; reg < 4; ++reg) w4[reg] = __shfl(wexp, kg * 4 + reg);

    float s1v[4] = {0.f, 0.f, 0.f, 0.f}, s2v[4] = {0.f, 0.f, 0.f, 0.f};
#pragma unroll
    for (int c = 0; c < 8; ++c)
#pragma unroll
      for (int reg = 0; reg < 4; ++reg) {
        float v = acc[rt][c][reg] + bi_r[c];
        acc[rt][c][reg] = v;
        s1v[reg] += v;
        s2v[reg] += v * v;
      }
#pragma unroll
    for (int off = 1; off <= 8; off <<= 1)
#pragma unroll
      for (int reg = 0; reg < 4; ++reg) {
        s1v[reg] += __shfl_xor(s1v[reg], off);
        s2v[reg] += __shfl_xor(s2v[reg], off);
      }
    float mu[4], rs[4];
#pragma unroll
    for (int reg = 0; reg < 4; ++reg) {
      mu[reg] = s1v[reg] * (1.0f / NFn);
      float var = s2v[reg] * (1.0f / NFn) - mu[reg] * mu[reg];
      rs[reg] = rsqrtf(var + LN_EPSn);
    }
#pragma unroll
    for (int c = 0; c < 8; ++c)
#pragma unroll
      for (int reg = 0; reg < 4; ++reg) {
        float feat = (acc[rt][c][reg] - mu[reg]) * rs[reg] * g_r[c] + be_r[c];
        lt[(wv * 32 + rt * 16 + kg * 4 + reg) * RECS + c * 16 + colb] =
            f2bf(feat * w4[reg]);
      }
  }
  __syncthreads();

  // -------- write records to sorted positions (2 threads per row) --------
  const int row = tid >> 1, half = tid & 1;
  const int gr = blockIdx.x * 128 + row;
  if (gr < RFn) {
    int4* dst = (int4*)(buf + (size_t)inv[gr] * RECB);
    const int4* src = (const int4*)(&lt[row * RECS]);
    if (half == 0) {
#pragma unroll
      for (int i = 0; i < 8; ++i) dst[i] = src[i];
    } else {
#pragma unroll
      for (int i = 8; i < 17; ++i) dst[i] = src[i];
    }
  }
}

// ---------------------------------------------------------------------------
// Phase B: one wave per segment. Records are contiguous per segment: stream
// them, accumulate Sum(feat*w) (2 cols/lane) and Sum(w), write out num/den.
// ---------------------------------------------------------------------------
__global__ __launch_bounds__(256) void reduce_kernel(
    const char* __restrict__ buf, const int* __restrict__ rowstart,
    float* __restrict__ out) {
  const int lane = threadIdx.x & 63;
  const int seg = blockIdx.x * 4 + (threadIdx.x >> 6);
  if (seg >= RAn) return;
  const int rb = rowstart[seg], re = rowstart[seg + 1];
  if (re <= rb) return;  // empty: out stays 0 (memset)
  float a0 = 0.f, a1 = 0.f, wsum = 0.f;
  for (int p = rb; p < re; ++p) {
    const char* rec = buf + (size_t)p * RECB;
    unsigned v = *(const unsigned*)(rec + lane * 4);
    a0 += __builtin_bit_cast(float, v << 16);
    a1 += __builtin_bit_cast(float, v & 0xffff0000u);
    wsum += *(const float*)(rec + 256);
  }
  float2 o;
  o.x = a0 / wsum;
  o.y = a1 / wsum;
  *(float2*)(out + (size_t)seg * NFn + lane * 2) = o;
}

// ---------------------------------------------------------------------------
// Fallback path (small ws): round-1 atomic kernel, known-good at 375 us.
// ---------------------------------------------------------------------------
__global__ __launch_bounds__(256) void main_atomic(
    const float* __restrict__ X, const short* __restrict__ fragWS,
    const float* __restrict__ Wa, const float* __restrict__ ba,
    const float* __restrict__ bfeat, const float* __restrict__ gamma,
    const float* __restrict__ beta, const int* __restrict__ res_index,
    float* __restrict__ Nacc, float* __restrict__ D) {
  __shared__ short sB[4096 * 8];
  const int tid = threadIdx.x;
  {
    const int4* src = (const int4*)fragWS;
    int4* dst = (int4*)sB;
#pragma unroll 4
    for (int i = tid; i < 4096; i += 256) dst[i] = src[i];
  }
  __syncthreads();
  const int lane = tid & 63;
  const int wv = tid >> 6;
  const int rowbase = blockIdx.x * 128 + wv * 32;
  const int colb = lane & 15;
  const int kg = lane >> 4;
  float g_r[8], be_r[8], bi_r[8];
#pragma unroll
  for (int c = 0; c < 8; ++c) {
    int col = c * 16 + colb;
    g_r[c] = gamma[col];
    be_r[c] = beta[col];
    bi_r[c] = bfeat[col];
  }
  const float batn = ba[0];
  f32x4 acc[2][8];
#pragma unroll
  for (int rt = 0; rt < 2; ++rt)
#pragma unroll
    for (int c = 0; c < 8; ++c) acc[rt][c] = (f32x4)(0.0f);
  float logit[2] = {0.f, 0.f};
  int gr0 = rowbase + colb;
  int gr1 = gr0 + 16;
  long r0 = (gr0 < RFn) ? gr0 : (RFn - 1);
  long r1 = (gr1 < RFn) ? gr1 : (RFn - 1);
  const float* xp0 = X + r0 * F1n + kg * 8;
  const float* xp1 = X + r1 * F1n + kg * 8;
#pragma unroll
  for (int s = 0; s < 8; ++s) {
    short8 bfr[8];
#pragma unroll
    for (int c = 0; c < 8; ++c)
      bfr[c] = *(const short8*)(sB + (((s * 8 + c) * 64 + lane) * 8));
    const float4 wa0 = *(const float4*)(Wa + s * 32 + kg * 8);
    const float4 wa1 = *(const float4*)(Wa + s * 32 + kg * 8 + 4);
#pragma unroll
    for (int rt = 0; rt < 2; ++rt) {
      const float* xp = rt ? xp1 : xp0;
      const float4 x0 = *(const float4*)(xp + s * 32);
      const float4 x1 = *(const float4*)(xp + s * 32 + 4);
      float a0 = fmaxf(x0.x, 0.01f * x0.x);
      float a1 = fmaxf(x0.y, 0.01f * x0.y);
      float a2 = fmaxf(x0.z, 0.01f * x0.z);
      float a3 = fmaxf(x0.w, 0.01f * x0.w);
      float a4 = fmaxf(x1.x, 0.01f * x1.x);
      float a5 = fmaxf(x1.y, 0.01f * x1.y);
      float a6 = fmaxf(x1.z, 0.01f * x1.z);
      float a7 = fmaxf(x1.w, 0.01f * x1.w);
      logit[rt] += a0 * wa0.x + a1 * wa0.y + a2 * wa0.z + a3 * wa0.w +
                   a4 * wa1.x + a5 * wa1.y + a6 * wa1.z + a7 * wa1.w;
      short8 af;
      af[0] = f2bf(a0); af[1] = f2bf(a1); af[2] = f2bf(a2); af[3] = f2bf(a3);
      af[4] = f2bf(a4); af[5] = f2bf(a5); af[6] = f2bf(a6); af[7] = f2bf(a7);
#pragma unroll
      for (int c = 0; c < 8; ++c)
        acc[rt][c] = __builtin_amdgcn_mfma_f32_16x16x32_bf16(af, bfr[c],
                                                             acc[rt][c], 0, 0, 0);
    }
  }
#pragma unroll
  for (int rt = 0; rt < 2; ++rt) {
    float lg = logit[rt];
    lg += __shfl_xor(lg, 16);
    lg += __shfl_xor(lg, 32);
    const float wexp = __expf(lg + batn);
    const int gr = rowbase + rt * 16 + colb;
    const int seg = res_index[(gr < RFn) ? gr : (RFn - 1)];
    if (lane < 16 && gr < RFn) atomicAdd(&D[seg], wexp);
    float w4[4];
    int s4[4], v4[4];
#pragma unroll
    for (int reg = 0; reg < 4; ++reg) {
      int srcl = kg * 4 + reg;
      w4[reg] = __shfl(wexp, srcl);
      s4[reg] = __shfl(seg, srcl);
      v4[reg] = (rowbase + rt * 16 + srcl) < RFn;
    }
    float s1v[4] = {0.f, 0.f, 0.f, 0.f}, s2v[4] = {0.f, 0.f, 0.f, 0.f};
#pragma unroll
    for (int c = 0; c < 8; ++c)
#pragma unroll
      for (int reg = 0; reg < 4; ++reg) {
        float t = acc[rt][c][reg] + bi_r[c];
        acc[rt][c][reg] = t;
        s1v[reg] += t;
        s2v[reg] += t * t;
      }
#pragma unroll
    for (int off = 1; off <= 8; off <<= 1)
#pragma unroll
      for (int reg = 0; reg < 4; ++reg) {
        s1v[reg] += __shfl_xor(s1v[reg], off);
        s2v[reg] += __shfl_xor(s2v[reg], off);
      }
    float mu[4], rs[4];
#pragma unroll
    for (int reg = 0; reg < 4; ++reg) {
      mu[reg] = s1v[reg] * (1.0f / NFn);
      float var = s2v[reg] * (1.0f / NFn) - mu[reg] * mu[reg];
      rs[reg] = rsqrtf(var + LN_EPSn);
    }
#pragma unroll
    for (int c = 0; c < 8; ++c)
#pragma unroll
      for (int reg = 0; reg < 4; ++reg) {
        if (v4[reg]) {
          float feat = (acc[rt][c][reg] - mu[reg]) * rs[reg] * g_r[c] + be_r[c];
          atomicAdd(Nacc + (size_t)s4[reg] * NFn + c * 16 + colb, feat * w4[reg]);
        }
      }
  }
}

__global__ void div_kernel(float* __restrict__ out, const float* __restrict__ D) {
  int i = blockIdx.x * 256 + threadIdx.x;
  if (i < RAn * NFn) {
    float d = D[i >> 7];
    out[i] = (d > 0.f) ? out[i] / d : 0.f;
  }
}

extern "C" void kernel_launch(void* const* d_in, const int* in_sizes, int n_in,
                              void* d_out, int out_size, void* d_ws, size_t ws_size,
                              hipStream_t stream) {
  const float* X = (const float*)d_in[0];
  const float* Wf = (const float*)d_in[1];
  const float* bfeat = (const float*)d_in[2];
  const float* gamma = (const float*)d_in[3];
  const float* beta = (const float*)d_in[4];
  const float* Wa = (const float*)d_in[5];
  const float* ba = (const float*)d_in[6];
  const int* ri = (const int*)d_in[7];
  float* out = (float*)d_out;

  char* ws = (char*)d_ws;
  short* frag = (short*)ws;                  // 65,536 B
  const size_t NEED = 2667648ULL + (size_t)RFn * RECB;  // ~138.7 MB

  prep_kernel<<<16, 256, 0, stream>>>(Wf, frag);
  hipMemsetAsync(out, 0, (size_t)RAn * NFn * sizeof(float), stream);

  if (ws_size >= NEED) {
    int* hist = (int*)(ws + 65536);
    int* rowstart = (int*)(ws + 266240);     // (RAn+1) ints
    int* cursor = (int*)(ws + 466944);
    int* inv = (int*)(ws + 667648);          // RFn ints
    char* buf = ws + 2667648;                // RFn * 272 B

    hipMemsetAsync(hist, 0, (size_t)RAn * sizeof(int), stream);
    hist_kernel<<<(RFn + 255) / 256, 256, 0, stream>>>(ri, hist);
    scan_kernel<<<1, 1024, 0, stream>>>(hist, rowstart, cursor);
    scatter_kernel<<<(RFn + 255) / 256, 256, 0, stream>>>(ri, cursor, inv);
    featw_kernel<<<(RFn + 127) / 128, 256, 0, stream>>>(X, frag, Wa, ba, bfeat,
                                                        gamma, beta, inv, buf);
    reduce_kernel<<<(RAn + 3) / 4, 256, 0, stream>>>(buf, rowstart, out);
  } else {
    float* D = (float*)(ws + 65536);
    hipMemsetAsync(D, 0, (size_t)RAn * sizeof(float), stream);
    main_atomic<<<(RFn + 127) / 128, 256, 0, stream>>>(X, frag, Wa, ba, bfeat,
                                                       gamma, beta, ri, out, D);
    div_kernel<<<(RAn * NFn + 255) / 256, 256, 0, stream>>>(out, D);
  }
}

// Round 4
// 321.391 us; speedup vs baseline: 2.0972x; 1.5938x over previous
//
#include <hip/hip_runtime.h>
#include <hip/hip_bf16.h>

#define RFn 500000
#define F1n 256
#define NFn 128
#define RAn 50000
#define LN_EPSn 1e-5f
#define RECB 272          // record bytes: 128 bf16 feat*w + f32 w + 12B pad
#define RECS 136
#define NTILE (RFn / 16)  // 31250 16-row tiles (RFn % 16 == 0)
#define NWAVE 4096        // featw grid (1 wave per block)
#define ROWPAD 1040       // LDS bytes per row (1024 + 16 pad -> even bank spread)
#define BUFB (16 * ROWPAD)  // 16640 per buffer
#define SCB 256
#define SCG ((RAn + SCB - 1) / SCB)  // 196

typedef float f32x4 __attribute__((ext_vector_type(4)));
typedef short short8 __attribute__((ext_vector_type(8)));

__device__ __forceinline__ short f2bf(float f) {
  __hip_bfloat16 h = __float2bfloat16(f);  // RNE
  return __builtin_bit_cast(short, h);
}

__device__ __forceinline__ void gload_lds16(const void* g, void* l) {
  __builtin_amdgcn_global_load_lds(
      (const __attribute__((address_space(1))) void*)g,
      (__attribute__((address_space(3))) void*)l, 16, 0, 0);
}

// ---------------------------------------------------------------------------
// Pack W_feat (256x128 f32) into MFMA B-frag image: frag (s,c), lane l:
// col = c*16+(l&15), k = s*32+(l>>4)*8+i  (8 bf16 per lane).
// ---------------------------------------------------------------------------
__global__ void prep_kernel(const float* __restrict__ Wf, short* __restrict__ frag) {
  int p = blockIdx.x * blockDim.x + threadIdx.x;  // 0..4095
  if (p >= 4096) return;
  int f = p >> 6, l = p & 63;
  int s = f >> 3, c = f & 7;
  int col = c * 16 + (l & 15);
  int k0 = s * 32 + ((l >> 4) << 3);
  short8 v;
#pragma unroll
  for (int i = 0; i < 8; ++i) v[i] = f2bf(Wf[(k0 + i) * NFn + col]);
  *(short8*)(frag + (size_t)p * 8) = v;
}

__global__ void hist_kernel(const int* __restrict__ ri, int* __restrict__ hist) {
  int i = blockIdx.x * 256 + threadIdx.x;
  if (i < RFn) atomicAdd(&hist[ri[i]], 1);
}

// block-local exclusive scan -> T, block totals -> bsum
__global__ __launch_bounds__(256) void scanA_kernel(const int* __restrict__ hist,
                                                    int* __restrict__ T,
                                                    int* __restrict__ bsum) {
  __shared__ int ls[256];
  const int t = threadIdx.x, idx = blockIdx.x * 256 + t;
  const int v = (idx < RAn) ? hist[idx] : 0;
  ls[t] = v;
  __syncthreads();
  for (int off = 1; off < 256; off <<= 1) {
    int add = (t >= off) ? ls[t - off] : 0;
    __syncthreads();
    ls[t] += add;
    __syncthreads();
  }
  if (idx < RAn) T[idx] = ls[t] - v;
  if (t == 255) bsum[blockIdx.x] = ls[255];
}

__global__ __launch_bounds__(256) void scanB_kernel(int* __restrict__ bsum,
                                                    int* __restrict__ boff) {
  __shared__ int ls[256];
  const int t = threadIdx.x;
  const int v = (t < SCG) ? bsum[t] : 0;
  ls[t] = v;
  __syncthreads();
  for (int off = 1; off < 256; off <<= 1) {
    int add = (t >= off) ? ls[t - off] : 0;
    __syncthreads();
    ls[t] += add;
    __syncthreads();
  }
  if (t < SCG) boff[t] = ls[t] - v;
}

__global__ __launch_bounds__(256) void scanC_kernel(const int* __restrict__ T,
                                                    const int* __restrict__ boff,
                                                    int* __restrict__ rowstart,
                                                    int* __restrict__ cursor) {
  const int idx = blockIdx.x * 256 + threadIdx.x;
  if (idx < RAn) {
    int v = T[idx] + boff[blockIdx.x];
    rowstart[idx] = v;
    cursor[idx] = v;
  }
  if (idx == 0) rowstart[RAn] = RFn;
}

// inv[i] = sorted position of original row i (segment-major order)
__global__ void scatter_kernel(const int* __restrict__ ri, int* __restrict__ cursor,
                               int* __restrict__ inv) {
  int i = blockIdx.x * 256 + threadIdx.x;
  if (i < RFn) inv[i] = atomicAdd(&cursor[ri[i]], 1);
}

// ---------------------------------------------------------------------------
// featw2: 1 wave per block, wave-private double-buffered LDS X-tile staged via
// global_load_lds (deep async queue, no VGPR cost, no barriers). Per tile:
// vmcnt(0) -> issue next tile's 16 row-loads -> compute (ds_read_b128 + MFMA +
// LN + logit/exp) -> transpose records through the dead buffer -> scattered
// 272B record stores at inv[] positions.
// ---------------------------------------------------------------------------
__global__ __launch_bounds__(64) void featw2_kernel(
    const float* __restrict__ X, const short* __restrict__ fragWS,
    const float* __restrict__ Wa, const float* __restrict__ ba,
    const float* __restrict__ bfeat, const float* __restrict__ gamma,
    const float* __restrict__ beta, const int* __restrict__ inv,
    char* __restrict__ buf) {
  __shared__ __attribute__((aligned(16))) char lds[2 * BUFB];  // 33280 B

  const int lane = threadIdx.x;
  const int colb = lane & 15;
  const int kg = lane >> 4;

  float g_r[8], be_r[8], bi_r[8];
#pragma unroll
  for (int c = 0; c < 8; ++c) {
    int col = c * 16 + colb;
    g_r[c] = gamma[col];
    be_r[c] = beta[col];
    bi_r[c] = bfeat[col];
  }
  const float batn = ba[0];

  int t = blockIdx.x;  // < NWAVE <= NTILE
  // prologue: stage tile t into buffer 0
  {
    const float* xr = X + (size_t)t * 16 * F1n;
#pragma unroll
    for (int r = 0; r < 16; ++r)
      gload_lds16(xr + r * F1n + lane * 4, &lds[r * ROWPAD]);
  }
  int cur = 0;

  while (true) {
    const int tn = t + NWAVE;
    const bool more = (tn < NTILE);

    asm volatile("s_waitcnt vmcnt(0)" ::: "memory");
    __builtin_amdgcn_sched_barrier(0);

    if (more) {  // stage next tile into other buffer; overlaps compute below
      const float* xr = X + (size_t)tn * 16 * F1n;
      char* db = &lds[(cur ^ 1) * BUFB];
#pragma unroll
      for (int r = 0; r < 16; ++r)
        gload_lds16(xr + r * F1n + lane * 4, db + r * ROWPAD);
    }

    // -------- compute tile t from lds[cur] --------
    const char* A = &lds[cur * BUFB];
    f32x4 acc[8];
#pragma unroll
    for (int c = 0; c < 8; ++c) acc[c] = (f32x4)(0.0f);
    float logit = 0.f;

#pragma unroll
    for (int s = 0; s < 8; ++s) {
      short8 bfr[8];
#pragma unroll
      for (int c = 0; c < 8; ++c)
        bfr[c] = *(const short8*)(fragWS + (((s * 8 + c) * 64 + lane) * 8));
      const float4 wa0 = *(const float4*)(Wa + s * 32 + kg * 8);
      const float4 wa1 = *(const float4*)(Wa + s * 32 + kg * 8 + 4);
      const float4 x0 = *(const float4*)(A + colb * ROWPAD + s * 128 + kg * 32);
      const float4 x1 = *(const float4*)(A + colb * ROWPAD + s * 128 + kg * 32 + 16);
      float a0 = fmaxf(x0.x, 0.01f * x0.x);
      float a1 = fmaxf(x0.y, 0.01f * x0.y);
      float a2 = fmaxf(x0.z, 0.01f * x0.z);
      float a3 = fmaxf(x0.w, 0.01f * x0.w);
      float a4 = fmaxf(x1.x, 0.01f * x1.x);
      float a5 = fmaxf(x1.y, 0.01f * x1.y);
      float a6 = fmaxf(x1.z, 0.01f * x1.z);
      float a7 = fmaxf(x1.w, 0.01f * x1.w);
      logit += a0 * wa0.x + a1 * wa0.y + a2 * wa0.z + a3 * wa0.w +
               a4 * wa1.x + a5 * wa1.y + a6 * wa1.z + a7 * wa1.w;
      short8 af;
      af[0] = f2bf(a0); af[1] = f2bf(a1); af[2] = f2bf(a2); af[3] = f2bf(a3);
      af[4] = f2bf(a4); af[5] = f2bf(a5); af[6] = f2bf(a6); af[7] = f2bf(a7);
#pragma unroll
      for (int c = 0; c < 8; ++c)
        acc[c] = __builtin_amdgcn_mfma_f32_16x16x32_bf16(af, bfr[c], acc[c], 0, 0, 0);
    }

    // -------- epilogue: w, LN, records into dead buffer lds[cur] --------
    char* lt = &lds[cur * BUFB];
    {
      float lg = logit;
      lg += __shfl_xor(lg, 16);
      lg += __shfl_xor(lg, 32);
      const float wexp = __expf(lg + batn);
      if (lane < 16) {
        *(float*)&lt[colb * RECB + 256] = wexp;
        *(int*)&lt[colb * RECB + 260] = 0;
        *(int*)&lt[colb * RECB + 264] = 0;
        *(int*)&lt[colb * RECB + 268] = 0;
      }
      float w4[4];
#pragma unroll
      for (int reg = 0; reg < 4; ++reg) w4[reg] = __shfl(wexp, kg * 4 + reg);

      float s1v[4] = {0.f, 0.f, 0.f, 0.f}, s2v[4] = {0.f, 0.f, 0.f, 0.f};
#pragma unroll
      for (int c = 0; c < 8; ++c)
#pragma unroll
        for (int reg = 0; reg < 4; ++reg) {
          float v = acc[c][reg] + bi_r[c];
          acc[c][reg] = v;
          s1v[reg] += v;
          s2v[reg] += v * v;
        }
#pragma unroll
      for (int off = 1; off <= 8; off <<= 1)
#pragma unroll
        for (int reg = 0; reg < 4; ++reg) {
          s1v[reg] += __shfl_xor(s1v[reg], off);
          s2v[reg] += __shfl_xor(s2v[reg], off);
        }
#pragma unroll
      for (int reg = 0; reg < 4; ++reg) {
        float mu = s1v[reg] * (1.0f / NFn);
        float var = s2v[reg] * (1.0f / NFn) - mu * mu;
        float rs = rsqrtf(var + LN_EPSn);
#pragma unroll
        for (int c = 0; c < 8; ++c) {
          float feat = (acc[c][reg] - mu) * rs * g_r[c] + be_r[c];
          ((short*)lt)[(kg * 4 + reg) * RECS + c * 16 + colb] = f2bf(feat * w4[reg]);
        }
      }
    }

    // -------- write records to sorted positions (4 lanes per row) --------
    {
      const int r = lane >> 2, j = lane & 3;
      char* dst = buf + (size_t)inv[t * 16 + r] * RECB;
      int4 v0 = *(const int4*)&lt[r * RECB + j * 16];
      int4 v1 = *(const int4*)&lt[r * RECB + (j + 4) * 16];
      int4 v2 = *(const int4*)&lt[r * RECB + (j + 8) * 16];
      int4 v3 = *(const int4*)&lt[r * RECB + (j + 12) * 16];
      *(int4*)(dst + j * 16) = v0;
      *(int4*)(dst + (j + 4) * 16) = v1;
      *(int4*)(dst + (j + 8) * 16) = v2;
      *(int4*)(dst + (j + 12) * 16) = v3;
      if (j == 0) {
        int4 v4 = *(const int4*)&lt[r * RECB + 256];
        *(int4*)(dst + 256) = v4;
      }
    }

    if (!more) break;
    cur ^= 1;
    t = tn;
  }
}

// ---------------------------------------------------------------------------
// reduce: one wave per segment; records are contiguous per segment. Writes
// every segment (zeros for empty) so no out-memset is needed.
// ---------------------------------------------------------------------------
__global__ __launch_bounds__(256) void reduce_kernel(
    const char* __restrict__ buf, const int* __restrict__ rowstart,
    float* __restrict__ out) {
  const int lane = threadIdx.x & 63;
  const int seg = blockIdx.x * 4 + (threadIdx.x >> 6);
  if (seg >= RAn) return;
  const int rb = rowstart[seg], re = rowstart[seg + 1];
  float a0 = 0.f, a1 = 0.f, wsum = 0.f;
  for (int p = rb; p < re; ++p) {
    const char* rec = buf + (size_t)p * RECB;
    unsigned v = *(const unsigned*)(rec + lane * 4);
    a0 += __builtin_bit_cast(float, v << 16);
    a1 += __builtin_bit_cast(float, v & 0xffff0000u);
    wsum += *(const float*)(rec + 256);
  }
  float2 o;
  if (re > rb) {
    o.x = a0 / wsum;
    o.y = a1 / wsum;
  } else {
    o.x = 0.f;
    o.y = 0.f;
  }
  *(float2*)(out + (size_t)seg * NFn + lane * 2) = o;
}

// ---------------------------------------------------------------------------
// Fallback path (small ws): round-1 atomic kernel, known-good at 375 us.
// ---------------------------------------------------------------------------
__global__ __launch_bounds__(256) void main_atomic(
    const float* __restrict__ X, const short* __restrict__ fragWS,
    const float* __restrict__ Wa, const float* __restrict__ ba,
    const float* __restrict__ bfeat, const float* __restrict__ gamma,
    const float* __restrict__ beta, const int* __restrict__ res_index,
    float* __restrict__ Nacc, float* __restrict__ D) {
  __shared__ short sB[4096 * 8];
  const int tid = threadIdx.x;
  {
    const int4* src = (const int4*)fragWS;
    int4* dst = (int4*)sB;
#pragma unroll 4
    for (int i = tid; i < 4096; i += 256) dst[i] = src[i];
  }
  __syncthreads();
  const int lane = tid & 63;
  const int wv = tid >> 6;
  const int rowbase = blockIdx.x * 128 + wv * 32;
  const int colb = lane & 15;
  const int kg = lane >> 4;
  float g_r[8], be_r[8], bi_r[8];
#pragma unroll
  for (int c = 0; c < 8; ++c) {
    int col = c * 16 + colb;
    g_r[c] = gamma[col];
    be_r[c] = beta[col];
    bi_r[c] = bfeat[col];
  }
  const float batn = ba[0];
  f32x4 acc[2][8];
#pragma unroll
  for (int rt = 0; rt < 2; ++rt)
#pragma unroll
    for (int c = 0; c < 8; ++c) acc[rt][c] = (f32x4)(0.0f);
  float logit[2] = {0.f, 0.f};
  int gr0 = rowbase + colb;
  int gr1 = gr0 + 16;
  long r0 = (gr0 < RFn) ? gr0 : (RFn - 1);
  long r1 = (gr1 < RFn) ? gr1 : (RFn - 1);
  const float* xp0 = X + r0 * F1n + kg * 8;
  const float* xp1 = X + r1 * F1n + kg * 8;
#pragma unroll
  for (int s = 0; s < 8; ++s) {
    short8 bfr[8];
#pragma unroll
    for (int c = 0; c < 8; ++c)
      bfr[c] = *(const short8*)(sB + (((s * 8 + c) * 64 + lane) * 8));
    const float4 wa0 = *(const float4*)(Wa + s * 32 + kg * 8);
    const float4 wa1 = *(const float4*)(Wa + s * 32 + kg * 8 + 4);
#pragma unroll
    for (int rt = 0; rt < 2; ++rt) {
      const float* xp = rt ? xp1 : xp0;
      const float4 x0 = *(const float4*)(xp + s * 32);
      const float4 x1 = *(const float4*)(xp + s * 32 + 4);
      float a0 = fmaxf(x0.x, 0.01f * x0.x);
      float a1 = fmaxf(x0.y, 0.01f * x0.y);
      float a2 = fmaxf(x0.z, 0.01f * x0.z);
      float a3 = fmaxf(x0.w, 0.01f * x0.w);
      float a4 = fmaxf(x1.x, 0.01f * x1.x);
      float a5 = fmaxf(x1.y, 0.01f * x1.y);
      float a6 = fmaxf(x1.z, 0.01f * x1.z);
      float a7 = fmaxf(x1.w, 0.01f * x1.w);
      logit[rt] += a0 * wa0.x + a1 * wa0.y + a2 * wa0.z + a3 * wa0.w +
                   a4 * wa1.x + a5 * wa1.y + a6 * wa1.z + a7 * wa1.w;
      short8 af;
      af[0] = f2bf(a0); af[1] = f2bf(a1); af[2] = f2bf(a2); af[3] = f2bf(a3);
      af[4] = f2bf(a4); af[5] = f2bf(a5); af[6] = f2bf(a6); af[7] = f2bf(a7);
#pragma unroll
      for (int c = 0; c < 8; ++c)
        acc[rt][c] = __builtin_amdgcn_mfma_f32_16x16x32_bf16(af, bfr[c],
                                                             acc[rt][c], 0, 0, 0);
    }
  }
#pragma unroll
  for (int rt = 0; rt < 2; ++rt) {
    float lg = logit[rt];
    lg += __shfl_xor(lg, 16);
    lg += __shfl_xor(lg, 32);
    const float wexp = __expf(lg + batn);
    const int gr = rowbase + rt * 16 + colb;
    const int seg = res_index[(gr < RFn) ? gr : (RFn - 1)];
    if (lane < 16 && gr < RFn) atomicAdd(&D[seg], wexp);
    float w4[4];
    int s4[4], v4[4];
#pragma unroll
    for (int reg = 0; reg < 4; ++reg) {
      int srcl = kg * 4 + reg;
      w4[reg] = __shfl(wexp, srcl);
      s4[reg] = __shfl(seg, srcl);
      v4[reg] = (rowbase + rt * 16 + srcl) < RFn;
    }
    float s1v[4] = {0.f, 0.f, 0.f, 0.f}, s2v[4] = {0.f, 0.f, 0.f, 0.f};
#pragma unroll
    for (int c = 0; c < 8; ++c)
#pragma unroll
      for (int reg = 0; reg < 4; ++reg) {
        float t2 = acc[rt][c][reg] + bi_r[c];
        acc[rt][c][reg] = t2;
        s1v[reg] += t2;
        s2v[reg] += t2 * t2;
      }
#pragma unroll
    for (int off = 1; off <= 8; off <<= 1)
#pragma unroll
      for (int reg = 0; reg < 4; ++reg) {
        s1v[reg] += __shfl_xor(s1v[reg], off);
        s2v[reg] += __shfl_xor(s2v[reg], off);
      }
    float mu[4], rs[4];
#pragma unroll
    for (int reg = 0; reg < 4; ++reg) {
      mu[reg] = s1v[reg] * (1.0f / NFn);
      float var = s2v[reg] * (1.0f / NFn) - mu[reg] * mu[reg];
      rs[reg] = rsqrtf(var + LN_EPSn);
    }
#pragma unroll
    for (int c = 0; c < 8; ++c)
#pragma unroll
      for (int reg = 0; reg < 4; ++reg) {
        if (v4[reg]) {
          float feat = (acc[rt][c][reg] - mu[reg]) * rs[reg] * g_r[c] + be_r[c];
          atomicAdd(Nacc + (size_t)s4[reg] * NFn + c * 16 + colb, feat * w4[reg]);
        }
      }
  }
}

__global__ void div_kernel(float* __restrict__ out, const float* __restrict__ D) {
  int i = blockIdx.x * 256 + threadIdx.x;
  if (i < RAn * NFn) {
    float d = D[i >> 7];
    out[i] = (d > 0.f) ? out[i] / d : 0.f;
  }
}

extern "C" void kernel_launch(void* const* d_in, const int* in_sizes, int n_in,
                              void* d_out, int out_size, void* d_ws, size_t ws_size,
                              hipStream_t stream) {
  const float* X = (const float*)d_in[0];
  const float* Wf = (const float*)d_in[1];
  const float* bfeat = (const float*)d_in[2];
  const float* gamma = (const float*)d_in[3];
  const float* beta = (const float*)d_in[4];
  const float* Wa = (const float*)d_in[5];
  const float* ba = (const float*)d_in[6];
  const int* ri = (const int*)d_in[7];
  float* out = (float*)d_out;

  char* ws = (char*)d_ws;
  short* frag = (short*)ws;  // 65,536 B

  // workspace layout (sort path)
  int* hist = (int*)(ws + 65536);        // 200,000 B
  int* T = (int*)(ws + 265536);          // 200,000 B
  int* bsum = (int*)(ws + 465536);       // 784 B
  int* boff = (int*)(ws + 466320);       // 784 B
  int* rowstart = (int*)(ws + 467104);   // 200,004 B
  int* cursor = (int*)(ws + 667108);     // 200,000 B
  int* inv = (int*)(ws + 867108);        // 2,000,000 B
  char* buf = ws + 2867120;              // 136,000,000 B
  const size_t NEED = 2867120ULL + (size_t)RFn * RECB;  // ~138.9 MB

  prep_kernel<<<16, 256, 0, stream>>>(Wf, frag);

  if (ws_size >= NEED) {
    hipMemsetAsync(hist, 0, (size_t)RAn * sizeof(int), stream);
    hist_kernel<<<(RFn + 255) / 256, 256, 0, stream>>>(ri, hist);
    scanA_kernel<<<SCG, 256, 0, stream>>>(hist, T, bsum);
    scanB_kernel<<<1, 256, 0, stream>>>(bsum, boff);
    scanC_kernel<<<SCG, 256, 0, stream>>>(T, boff, rowstart, cursor);
    scatter_kernel<<<(RFn + 255) / 256, 256, 0, stream>>>(ri, cursor, inv);
    featw2_kernel<<<NWAVE, 64, 0, stream>>>(X, frag, Wa, ba, bfeat, gamma, beta,
                                            inv, buf);
    reduce_kernel<<<(RAn + 3) / 4, 256, 0, stream>>>(buf, rowstart, out);
  } else {
    float* D = (float*)(ws + 65536);
    hipMemsetAsync(out, 0, (size_t)RAn * NFn * sizeof(float), stream);
    hipMemsetAsync(D, 0, (size_t)RAn * sizeof(float), stream);
    main_atomic<<<(RFn + 127) / 128, 256, 0, stream>>>(X, frag, Wa, ba, bfeat,
                                                       gamma, beta, ri, out, D);
    div_kernel<<<(RAn * NFn + 255) / 256, 256, 0, stream>>>(out, D);
  }
}